// Round 5
// baseline (37.852 us; speedup 1.0000x reference)
//
#include <hip/hip_runtime.h>
#include <math.h>

// Problem constants (from reference)
#define POOLD 50
#define GFD   45
#define DNND  400
#define ZIN   (POOLD + GFD)   // 95

// Parallel decomposition: 25 wgs x 16 output columns = 400 outputs/layer.
// Wave-local layout: lane = ol*16 + k0 ; each wave owns 4 outputs with a
// 16-way K-split INSIDE each 16-lane group -> reduction is 4 shfl_down ops,
// no cross-wave LDS tree, no __syncthreads on the reduce path.
#define NWG 25
#define BLK 256               // 4 waves
#define NK  (DNND / 16)       // 25 k-iters per lane per mid layer

// Exchange buffers in ws: one per produced activation vector, sentinel-filled
// with 0xFF bytes (negative NaN) each launch. Data IS the ready flag.
#define EXF   512             // floats per exchange buffer (2 KB aligned)
#define NEX   6               // dnn0 out + mid0..mid4 out (mid5 is fused)
#define SENT4 0xFFFFFFFFu

__device__ __forceinline__ float elu1(float x) {
    return x > 0.f ? x : expm1f(x);
}

// The entire GNN front-end is analytically dead:
//   global_mean_pool(BatchNorm_trainstats(h)) == bnpool_b  (exactly)
// so the output reduces to a tiny MLP on constants + gf1.
// v6 = v5 (ordinary launch, data-poll sync) with the per-layer cross-wave
// LDS tree reduction (5 __syncthreads/layer) replaced by wave-local
// shfl_down reduction (1 __syncthreads/layer). Producers publish 4B slots
// directly from the reducing lanes; consumers poll 8B pairs checking each
// half against the sentinel independently (4B halves are individually
// atomic, so no pairing race).
__global__ __launch_bounds__(BLK) void GATGraphModel_tail_v6(
    const float* __restrict__ gf1,        // [45]
    const float* __restrict__ bnpool_b,   // [14]
    const float* __restrict__ ugp1_W,     // [14,50]
    const float* __restrict__ ugp1_b,     // [50]
    const float* __restrict__ ugp2_W,     // [50,50]
    const float* __restrict__ ugp2_b,     // [50]
    const float* __restrict__ dnn0_W,     // [95,400]
    const float* __restrict__ dnn0_b,     // [400]
    const float* __restrict__ dnn_mid_W,  // [6,400,400]
    const float* __restrict__ dnn_mid_b,  // [6,400]
    const float* __restrict__ dnn_last_W, // [400,1]
    const float* __restrict__ dnn_last_b, // [1]
    float* __restrict__ out,              // [1]
    float* __restrict__ ws)               // 6*512f exchanges + 100f partials
{
    __shared__ float zs[DNND];     // staged activation vector
    __shared__ float red[128];     // wg0 final-gather scratch
    __shared__ float h2[POOLD];

    const int t    = threadIdx.x;
    const int lane = t & 63;
    const int wv   = t >> 6;            // wave 0..3
    const int k0   = lane & 15;         // K-slice within 16-lane group
    const int ol   = lane >> 4;         // output 0..3 within wave
    const int outi = blockIdx.x * 16 + wv * 4 + ol;  // this lane's output col

    float* finsl = ws + (size_t)NEX * EXF;   // [100] final partial sums

    // ---- preload dnn0 weight slice FIRST (overlaps the ugp dependent chain)
    float w0[6];
    #pragma unroll
    for (int j = 0; j < 6; ++j) {
        int k = k0 + j * 16; if (k > ZIN - 1) k = ZIN - 1;  // clamp; predicated at use
        w0[j] = dnn0_W[k * DNND + outi];
    }
    #pragma unroll
    for (int j = 0; j < 6; ++j) asm volatile("" : "+v"(w0[j]));

    // ---- ugp chain, redundantly in every wg (13 KB of cached reads —
    // cheaper than any exchange): p0 = bnpool_b ; h2 = p0@ugp1 + b
    if (t < POOLD) {
        float acc = ugp1_b[t];
        #pragma unroll
        for (int c = 0; c < 14; ++c) acc += bnpool_b[c] * ugp1_W[c * POOLD + t];
        h2[t] = acc;
    }
    __syncthreads();
    // p = h2 @ ugp2_W + b ; z = concat(p, gf1) -> zs[0:95]
    if (t < POOLD) {
        float acc = ugp2_b[t];
        #pragma unroll 10
        for (int k = 0; k < POOLD; ++k) acc += h2[k] * ugp2_W[k * POOLD + t];
        zs[t] = acc;
    } else if (t < ZIN) {
        zs[t] = gf1[t - POOLD];
    }
    __syncthreads();

    // ---- dnn0: elu(z95 @ dnn0_W + b) -> exchange 0, wave-local reduce
    {
        float acc = 0.f;
        #pragma unroll
        for (int j = 0; j < 6; ++j) {
            int k = k0 + j * 16;
            if (k < ZIN) acc += zs[k] * w0[j];
        }
        acc += __shfl_down(acc, 8, 16);
        acc += __shfl_down(acc, 4, 16);
        acc += __shfl_down(acc, 2, 16);
        acc += __shfl_down(acc, 1, 16);
        if (k0 == 0) {
            float v = elu1(acc + dnn0_b[outi]);
            __hip_atomic_store(&ws[outi], v,
                               __ATOMIC_RELAXED, __HIP_MEMORY_SCOPE_AGENT);
        }
    }

    // ---- 6 mid layers: z = elu(elu(z @ W + b)); layer i reads exchange i
    for (int i = 0; i < 6; ++i) {
        const float* __restrict__ W = dnn_mid_W + (size_t)i * DNND * DNND;

        // preload this lane's 25 weight elems + bias; pin in VGPRs so the
        // loads are in flight during the poll (compiler would sink them)
        float w[NK];
        #pragma unroll
        for (int j = 0; j < NK; ++j)
            w[j] = W[(k0 + j * 16) * DNND + outi];
        float bmid = dnn_mid_b[i * DNND + outi];
        #pragma unroll
        for (int j = 0; j < NK; ++j) asm volatile("" : "+v"(w[j]));
        asm volatile("" : "+v"(bmid));

        // poll the 8B slots of exchange i directly -> zs; each 4B half is
        // individually atomic, so check both halves against the sentinel
        const unsigned long long* s8 =
            (const unsigned long long*)(ws + (size_t)i * EXF);
        if (t < DNND / 2) {
            unsigned long long v;
            do {
                v = __hip_atomic_load(&s8[t], __ATOMIC_RELAXED,
                                      __HIP_MEMORY_SCOPE_AGENT);
            } while ((unsigned int)v == SENT4 ||
                     (unsigned int)(v >> 32) == SENT4);
            zs[2 * t]     = __uint_as_float((unsigned int)v);
            zs[2 * t + 1] = __uint_as_float((unsigned int)(v >> 32));
        }
        __syncthreads();   // the ONLY barrier on the per-layer path

        float acc = 0.f;
        #pragma unroll
        for (int j = 0; j < NK; ++j) acc += zs[k0 + j * 16] * w[j];
        acc += __shfl_down(acc, 8, 16);
        acc += __shfl_down(acc, 4, 16);
        acc += __shfl_down(acc, 2, 16);
        acc += __shfl_down(acc, 1, 16);

        if (k0 == 0) {
            float v = elu1(elu1(acc + bmid));
            if (i < 5) {
                __hip_atomic_store(&ws[(size_t)(i + 1) * EXF + outi], v,
                                   __ATOMIC_RELAXED, __HIP_MEMORY_SCOPE_AGENT);
            } else {
                // fused final dot: this lane's output x its last-layer weight,
                // summed across the wave's 4 outputs (lanes 0,16,32,48)
                float p = v * dnn_last_W[outi];
                p += __shfl_down(p, 16, 64);   // 0+=16, 32+=48
                p += __shfl_down(p, 32, 64);   // 0+=32
                if (lane == 0)
                    __hip_atomic_store(&finsl[blockIdx.x * 4 + wv], p,
                                       __ATOMIC_RELAXED,
                                       __HIP_MEMORY_SCOPE_AGENT);
            }
        }
    }

    // ---- wg0: gather 100 wave-partials, sigmoid
    if (blockIdx.x == 0) {
        if (t < 100) {
            float v;
            do {
                v = __hip_atomic_load(&finsl[t], __ATOMIC_RELAXED,
                                      __HIP_MEMORY_SCOPE_AGENT);
            } while (__float_as_uint(v) == SENT4);
            red[t] = v;
        }
        __syncthreads();
        if (t < 50) red[t] += red[t + 50];
        __syncthreads();
        if (t == 0) {
            float s = dnn_last_b[0];
            for (int j = 0; j < 50; ++j) s += red[j];
            out[0] = 1.f / (1.f + expf(-s));
        }
    }
}

extern "C" void kernel_launch(void* const* d_in, const int* in_sizes, int n_in,
                              void* d_out, int out_size, void* d_ws, size_t ws_size,
                              hipStream_t stream) {
    // setup_inputs() order:
    //  0 x, 1 edge_attr, 2 gf1, 3 bn_in_g, 4 bn_in_b,
    //  5 gat0_W, 6 gat0_asrc, 7 gat0_adst, 8 gat0_bias,
    //  9 gat_mid_W, 10 gat_mid_asrc, 11 gat_mid_adst, 12 gat_mid_bias,
    // 13 bn_mid_g, 14 bn_mid_b,
    // 15 gat_last_W, 16 gat_last_asrc, 17 gat_last_adst, 18 gat_last_bias,
    // 19 bnpool_g, 20 bnpool_b, 21 ugp1_W, 22 ugp1_b, 23 ugp2_W, 24 ugp2_b,
    // 25 dnn0_W, 26 dnn0_b, 27 dnn_mid_W, 28 dnn_mid_b, 29 dnn_last_W,
    // 30 dnn_last_b, 31 edge_index, 32 batch
    const float* gf1        = (const float*)d_in[2];
    const float* bnpool_b   = (const float*)d_in[20];
    const float* ugp1_W     = (const float*)d_in[21];
    const float* ugp1_b     = (const float*)d_in[22];
    const float* ugp2_W     = (const float*)d_in[23];
    const float* ugp2_b     = (const float*)d_in[24];
    const float* dnn0_W     = (const float*)d_in[25];
    const float* dnn0_b     = (const float*)d_in[26];
    const float* dnn_mid_W  = (const float*)d_in[27];
    const float* dnn_mid_b  = (const float*)d_in[28];
    const float* dnn_last_W = (const float*)d_in[29];
    const float* dnn_last_b = (const float*)d_in[30];
    float* out = (float*)d_out;
    float* ws  = (float*)d_ws;

    // Sentinel-fill the exchange region (6*2KB + 100*4B < 16KB) each replay.
    // 0xFF bytes = negative-NaN floats: unproducible by the kernel's finite
    // arithmetic, so "slot != sentinel" means "data ready".
    hipMemsetAsync(d_ws, 0xFF, 16384, stream);

    // Ordinary launch (graph-capturable; R4 proved this is worth ~22us).
    // Co-residency of all 25 blocks is guaranteed in practice: grid (25)
    // << CU count (256), trivial VGPR/LDS footprint.
    hipLaunchKernelGGL(GATGraphModel_tail_v6, dim3(NWG), dim3(BLK), 0, stream,
                       gf1, bnpool_b, ugp1_W, ugp1_b, ugp2_W, ugp2_b,
                       dnn0_W, dnn0_b, dnn_mid_W, dnn_mid_b,
                       dnn_last_W, dnn_last_b, out, ws);
}

// Round 6
// 22.300 us; speedup vs baseline: 1.6974x; 1.6974x over previous
//
#include <hip/hip_runtime.h>
#include <math.h>

// Problem constants (from reference)
#define POOLD 50
#define GFD   45
#define DNND  400
#define ZIN   (POOLD + GFD)   // 95

// Parallel decomposition: 25 wgs x 16 output columns = 400 outputs/layer.
// v5's coalesced mapping: t = kt*16 + tt ; tt = output lane (16 consecutive
// columns -> 4x64B segments per weight-load instruction), kt = 16-way
// K-split spanning the 4 waves (kt_local = lane>>4 inside each wave).
// Reduction: 2 intra-wave shfl_down (over kt_local) + one 64-float LDS
// combine -> 2 barriers/layer (v5 had 5; v6's shuffle-only layout broke
// load coalescing and cost +15us).
#define NWG 25
#define TT  16
#define BLK 256               // 4 waves
#define NK  (DNND / 16)       // 25 k-iters per thread per mid layer

// Exchange buffers in ws: one per produced activation vector, sentinel-filled
// with 0xFF bytes (negative NaN) each launch. Data IS the ready flag.
#define EXF   512             // floats per exchange buffer (2 KB aligned)
#define NEX   6               // dnn0 out + mid0..mid4 out (mid5 is fused)
#define SENT4 0xFFFFFFFFu

__device__ __forceinline__ float elu1(float x) {
    return x > 0.f ? x : expm1f(x);
}

// The entire GNN front-end is analytically dead:
//   global_mean_pool(BatchNorm_trainstats(h)) == bnpool_b  (exactly)
// so the output reduces to a tiny MLP on constants + gf1.
// v7 = v5 (ordinary launch, data-poll sync, coalesced loads) with the
// 5-barrier LDS tree replaced by shfl(32)+shfl(16) intra-wave reduction +
// a single 4-way LDS combine (2 barriers/layer). Publish is paired 8B
// atomic stores straight from wave 0; final dot + gather are pure shuffle.
__global__ __launch_bounds__(BLK) void GATGraphModel_tail_v7(
    const float* __restrict__ gf1,        // [45]
    const float* __restrict__ bnpool_b,   // [14]
    const float* __restrict__ ugp1_W,     // [14,50]
    const float* __restrict__ ugp1_b,     // [50]
    const float* __restrict__ ugp2_W,     // [50,50]
    const float* __restrict__ ugp2_b,     // [50]
    const float* __restrict__ dnn0_W,     // [95,400]
    const float* __restrict__ dnn0_b,     // [400]
    const float* __restrict__ dnn_mid_W,  // [6,400,400]
    const float* __restrict__ dnn_mid_b,  // [6,400]
    const float* __restrict__ dnn_last_W, // [400,1]
    const float* __restrict__ dnn_last_b, // [1]
    float* __restrict__ out,              // [1]
    float* __restrict__ ws)               // 6*512f exchanges + 25f partials
{
    __shared__ float zs[DNND];     // staged activation vector
    __shared__ float pr[64];       // 4 waves x 16 per-wave partials
    __shared__ float h2[POOLD];

    const int t     = threadIdx.x;
    const int tt    = t & (TT - 1);     // output col within wg's 16
    const int kt    = t >> 4;           // K-slice 0..15 (spans 4 waves)
    const int lane  = t & 63;
    const int wv    = t >> 6;           // wave 0..3
    const int tbase = blockIdx.x * TT;

    float* finsl = ws + (size_t)NEX * EXF;   // [25] final partial sums

    // ---- preload dnn0 weight slice FIRST (overlaps the ugp dependent chain)
    float w0[6];
    #pragma unroll
    for (int j = 0; j < 6; ++j) {
        int k = kt + j * TT; if (k > ZIN - 1) k = ZIN - 1;  // clamp; predicated at use
        w0[j] = dnn0_W[k * DNND + tbase + tt];
    }
    #pragma unroll
    for (int j = 0; j < 6; ++j) asm volatile("" : "+v"(w0[j]));
    const float wlast = dnn_last_W[tbase + tt];   // fused-final weight

    // ---- ugp chain, redundantly in every wg (13 KB of cached reads —
    // cheaper than any exchange): p0 = bnpool_b ; h2 = p0@ugp1 + b
    if (t < POOLD) {
        float acc = ugp1_b[t];
        #pragma unroll
        for (int c = 0; c < 14; ++c) acc += bnpool_b[c] * ugp1_W[c * POOLD + t];
        h2[t] = acc;
    }
    __syncthreads();
    // p = h2 @ ugp2_W + b ; z = concat(p, gf1) -> zs[0:95]
    if (t < POOLD) {
        float acc = ugp2_b[t];
        #pragma unroll 10
        for (int k = 0; k < POOLD; ++k) acc += h2[k] * ugp2_W[k * POOLD + t];
        zs[t] = acc;
    } else if (t < ZIN) {
        zs[t] = gf1[t - POOLD];
    }
    __syncthreads();

    // ---- dnn0: elu(z95 @ dnn0_W + b) -> exchange 0
    {
        float acc = 0.f;
        #pragma unroll
        for (int j = 0; j < 6; ++j) {
            int k = kt + j * TT;
            if (k < ZIN) acc += zs[k] * w0[j];
        }
        acc += __shfl_down(acc, 32, 64);    // fold kt_local 2,3 into 0,1
        acc += __shfl_down(acc, 16, 64);    // fold kt_local 1 into 0
        if (lane < TT) pr[wv * TT + lane] = acc;
        __syncthreads();
        if (t < TT) {
            float v = elu1(pr[t] + pr[TT + t] + pr[32 + t] + pr[48 + t]
                           + dnn0_b[tbase + t]);
            float hi = __shfl_down(v, 1, 16);
            if ((t & 1) == 0) {
                unsigned long long pv =
                    ((unsigned long long)__float_as_uint(hi) << 32) |
                    (unsigned long long)__float_as_uint(v);
                __hip_atomic_store((unsigned long long*)ws + (tbase >> 1) + (t >> 1),
                                   pv, __ATOMIC_RELAXED, __HIP_MEMORY_SCOPE_AGENT);
            }
        }
    }

    // ---- 6 mid layers: z = elu(elu(z @ W + b)); layer i reads exchange i
    for (int i = 0; i < 6; ++i) {
        const float* __restrict__ W = dnn_mid_W + (size_t)i * DNND * DNND;

        // preload this thread's 25 weight elems + bias; pin in VGPRs so the
        // loads are in flight during the poll (compiler would sink them).
        // Coalesced: per instruction a wave touches 4 rows x 16 consecutive
        // floats = 4x64B segments (v6's 64-line gather was the regression).
        float w[NK];
        #pragma unroll
        for (int j = 0; j < NK; ++j)
            w[j] = W[(kt + j * TT) * DNND + tbase + tt];
        float bmid = dnn_mid_b[i * DNND + tbase + tt];
        #pragma unroll
        for (int j = 0; j < NK; ++j) asm volatile("" : "+v"(w[j]));
        asm volatile("" : "+v"(bmid));

        // poll the 8B slots of exchange i directly -> zs; each 4B half is
        // individually atomic, so check both halves against the sentinel
        const unsigned long long* s8 =
            (const unsigned long long*)(ws + (size_t)i * EXF);
        if (t < DNND / 2) {
            unsigned long long v;
            do {
                v = __hip_atomic_load(&s8[t], __ATOMIC_RELAXED,
                                      __HIP_MEMORY_SCOPE_AGENT);
            } while ((unsigned int)v == SENT4 ||
                     (unsigned int)(v >> 32) == SENT4);
            zs[2 * t]     = __uint_as_float((unsigned int)v);
            zs[2 * t + 1] = __uint_as_float((unsigned int)(v >> 32));
        }
        __syncthreads();   // barrier 1: zs staged

        float acc = 0.f;
        #pragma unroll
        for (int j = 0; j < NK; ++j) acc += zs[kt + j * TT] * w[j];
        acc += __shfl_down(acc, 32, 64);
        acc += __shfl_down(acc, 16, 64);
        if (lane < TT) pr[wv * TT + lane] = acc;
        __syncthreads();   // barrier 2: partials visible

        if (t < TT) {
            float v = pr[t] + pr[TT + t] + pr[32 + t] + pr[48 + t] + bmid;
            v = elu1(elu1(v));
            if (i < 5) {
                float hi = __shfl_down(v, 1, 16);
                if ((t & 1) == 0) {
                    unsigned long long pv =
                        ((unsigned long long)__float_as_uint(hi) << 32) |
                        (unsigned long long)__float_as_uint(v);
                    __hip_atomic_store(
                        (unsigned long long*)(ws + (size_t)(i + 1) * EXF) +
                            (tbase >> 1) + (t >> 1),
                        pv, __ATOMIC_RELAXED, __HIP_MEMORY_SCOPE_AGENT);
                }
            } else {
                // fused final dot: 16 outputs x dnn_last_W, shuffle-reduced
                float p = v * wlast;   // wlast was loaded with tt==t here
                p += __shfl_down(p, 8, 16);
                p += __shfl_down(p, 4, 16);
                p += __shfl_down(p, 2, 16);
                p += __shfl_down(p, 1, 16);
                if (t == 0)
                    __hip_atomic_store(&finsl[blockIdx.x], p,
                                       __ATOMIC_RELAXED,
                                       __HIP_MEMORY_SCOPE_AGENT);
            }
        }
    }

    // ---- wg0, wave 0: gather 25 partials by shuffle, sigmoid
    if (blockIdx.x == 0 && wv == 0) {
        float p = 0.f;
        if (lane < NWG) {
            float v;
            do {
                v = __hip_atomic_load(&finsl[lane], __ATOMIC_RELAXED,
                                      __HIP_MEMORY_SCOPE_AGENT);
            } while (__float_as_uint(v) == SENT4);
            p = v;
        }
        p += __shfl_down(p, 32, 64);
        p += __shfl_down(p, 16, 64);
        p += __shfl_down(p, 8, 64);
        p += __shfl_down(p, 4, 64);
        p += __shfl_down(p, 2, 64);
        p += __shfl_down(p, 1, 64);
        if (lane == 0) {
            float s = p + dnn_last_b[0];
            out[0] = 1.f / (1.f + expf(-s));
        }
    }
}

extern "C" void kernel_launch(void* const* d_in, const int* in_sizes, int n_in,
                              void* d_out, int out_size, void* d_ws, size_t ws_size,
                              hipStream_t stream) {
    // setup_inputs() order:
    //  0 x, 1 edge_attr, 2 gf1, 3 bn_in_g, 4 bn_in_b,
    //  5 gat0_W, 6 gat0_asrc, 7 gat0_adst, 8 gat0_bias,
    //  9 gat_mid_W, 10 gat_mid_asrc, 11 gat_mid_adst, 12 gat_mid_bias,
    // 13 bn_mid_g, 14 bn_mid_b,
    // 15 gat_last_W, 16 gat_last_asrc, 17 gat_last_adst, 18 gat_last_bias,
    // 19 bnpool_g, 20 bnpool_b, 21 ugp1_W, 22 ugp1_b, 23 ugp2_W, 24 ugp2_b,
    // 25 dnn0_W, 26 dnn0_b, 27 dnn_mid_W, 28 dnn_mid_b, 29 dnn_last_W,
    // 30 dnn_last_b, 31 edge_index, 32 batch
    const float* gf1        = (const float*)d_in[2];
    const float* bnpool_b   = (const float*)d_in[20];
    const float* ugp1_W     = (const float*)d_in[21];
    const float* ugp1_b     = (const float*)d_in[22];
    const float* ugp2_W     = (const float*)d_in[23];
    const float* ugp2_b     = (const float*)d_in[24];
    const float* dnn0_W     = (const float*)d_in[25];
    const float* dnn0_b     = (const float*)d_in[26];
    const float* dnn_mid_W  = (const float*)d_in[27];
    const float* dnn_mid_b  = (const float*)d_in[28];
    const float* dnn_last_W = (const float*)d_in[29];
    const float* dnn_last_b = (const float*)d_in[30];
    float* out = (float*)d_out;
    float* ws  = (float*)d_ws;

    // Sentinel-fill the exchange region (6*2KB + 25*4B < 16KB) each replay.
    // 0xFF bytes = negative-NaN floats: unproducible by the kernel's finite
    // arithmetic, so "slot != sentinel" means "data ready".
    hipMemsetAsync(d_ws, 0xFF, 16384, stream);

    // Ordinary launch (graph-capturable; R4 proved this is worth ~22us).
    // Co-residency of all 25 blocks is guaranteed in practice: grid (25)
    // << CU count (256), trivial VGPR/LDS footprint.
    hipLaunchKernelGGL(GATGraphModel_tail_v7, dim3(NWG), dim3(BLK), 0, stream,
                       gf1, bnpool_b, ugp1_W, ugp1_b, ugp2_W, ugp2_b,
                       dnn0_W, dnn0_b, dnn_mid_W, dnn_mid_b,
                       dnn_last_W, dnn_last_b, out, ws);
}

// Round 7
// 18.703 us; speedup vs baseline: 2.0238x; 1.1923x over previous
//
#include <hip/hip_runtime.h>
#include <math.h>

// Problem constants (from reference)
#define POOLD 50
#define GFD   45
#define DNND  400
#define ZIN   (POOLD + GFD)   // 95

// Parallel decomposition: 25 wgs x 16 output columns = 400 outputs/layer.
// Coalesced mapping: t = kt*16 + tt ; tt = output lane (16 consecutive
// columns -> 4x64B segments per weight-load instruction), kt = 16-way
// K-split spanning the 4 waves. Reduction: 2 intra-wave shfl_down + one
// 4-way LDS combine -> 2 barriers/layer (v7 structure, unchanged).
#define NWG 25
#define TT  16
#define BLK 256               // 4 waves
#define NK  (DNND / 16)       // 25 k-iters per thread per mid layer

// v8: NO hipMemsetAsync. Exchange slots are 8B (tag:u32 | value:f32) pairs.
// A persistent epoch counter in ws is read once per run (G); all publishes
// are tagged G+1; block 0 stores G+1 back after the final gather (it can
// only reach that point after every block has published => every block has
// long since read G => no deadlock). Any uniform poison P in ws yields
// epoch=P and stale tags=P, polled tag P+1 never false-matches; stale data
// from our own previous run carries an older tag. So the protocol needs no
// initialization at all, and the graph is a single kernel node.
#define EXU   512             // u64 slots per exchange buffer (4 KB)
#define NEX   6               // dnn0 out + mid0..mid4 out (mid5 is fused)

__device__ __forceinline__ float elu1(float x) {
    return x > 0.f ? x : expm1f(x);
}

// The entire GNN front-end is analytically dead:
//   global_mean_pool(BatchNorm_trainstats(h)) == bnpool_b  (exactly)
// so the output reduces to a tiny MLP on constants + gf1.
__global__ __launch_bounds__(BLK) void GATGraphModel_tail_v8(
    const float* __restrict__ gf1,        // [45]
    const float* __restrict__ bnpool_b,   // [14]
    const float* __restrict__ ugp1_W,     // [14,50]
    const float* __restrict__ ugp1_b,     // [50]
    const float* __restrict__ ugp2_W,     // [50,50]
    const float* __restrict__ ugp2_b,     // [50]
    const float* __restrict__ dnn0_W,     // [95,400]
    const float* __restrict__ dnn0_b,     // [400]
    const float* __restrict__ dnn_mid_W,  // [6,400,400]
    const float* __restrict__ dnn_mid_b,  // [6,400]
    const float* __restrict__ dnn_last_W, // [400,1]
    const float* __restrict__ dnn_last_b, // [1]
    float* __restrict__ out,              // [1]
    float* __restrict__ ws)               // 6*4KB exchanges + finsl + epoch
{
    __shared__ float zs[DNND];     // staged activation vector
    __shared__ float pr[64];       // 4 waves x 16 per-wave partials
    __shared__ float h2[POOLD];

    const int t     = threadIdx.x;
    const int tt    = t & (TT - 1);     // output col within wg's 16
    const int kt    = t >> 4;           // K-slice 0..15 (spans 4 waves)
    const int lane  = t & 63;
    const int wv    = t >> 6;           // wave 0..3
    const int tbase = blockIdx.x * TT;

    unsigned long long* exb   = (unsigned long long*)ws;  // 6 x 512 u64
    unsigned long long* finsl = exb + (size_t)NEX * EXU;  // [25] tagged partials
    unsigned int*       epochp = (unsigned int*)(finsl + 32);

    // ---- epoch read (uniform across all blocks; one RT, overlapped with
    // the prologue below)
    const unsigned int tag =
        __hip_atomic_load(epochp, __ATOMIC_RELAXED, __HIP_MEMORY_SCOPE_AGENT) + 1u;
    const unsigned long long tagw = (unsigned long long)tag << 32;

    // ---- preload dnn0 weight slice FIRST (overlaps the ugp dependent chain)
    float w0[6];
    #pragma unroll
    for (int j = 0; j < 6; ++j) {
        int k = kt + j * TT; if (k > ZIN - 1) k = ZIN - 1;  // clamp; predicated at use
        w0[j] = dnn0_W[k * DNND + tbase + tt];
    }
    #pragma unroll
    for (int j = 0; j < 6; ++j) asm volatile("" : "+v"(w0[j]));
    const float wlast = dnn_last_W[tbase + tt];   // fused-final weight

    // ---- ugp chain, redundantly in every wg (13 KB of cached reads —
    // cheaper than any exchange): p0 = bnpool_b ; h2 = p0@ugp1 + b
    if (t < POOLD) {
        float acc = ugp1_b[t];
        #pragma unroll
        for (int c = 0; c < 14; ++c) acc += bnpool_b[c] * ugp1_W[c * POOLD + t];
        h2[t] = acc;
    }
    __syncthreads();
    // p = h2 @ ugp2_W + b ; z = concat(p, gf1) -> zs[0:95]
    if (t < POOLD) {
        float acc = ugp2_b[t];
        #pragma unroll 10
        for (int k = 0; k < POOLD; ++k) acc += h2[k] * ugp2_W[k * POOLD + t];
        zs[t] = acc;
    } else if (t < ZIN) {
        zs[t] = gf1[t - POOLD];
    }
    __syncthreads();

    // ---- dnn0: elu(z95 @ dnn0_W + b) -> exchange 0
    {
        float acc = 0.f;
        #pragma unroll
        for (int j = 0; j < 6; ++j) {
            int k = kt + j * TT;
            if (k < ZIN) acc += zs[k] * w0[j];
        }
        acc += __shfl_down(acc, 32, 64);    // fold kt 2,3 into 0,1
        acc += __shfl_down(acc, 16, 64);    // fold kt 1 into 0
        if (lane < TT) pr[wv * TT + lane] = acc;
        __syncthreads();
        if (t < TT) {
            float v = elu1(pr[t] + pr[TT + t] + pr[32 + t] + pr[48 + t]
                           + dnn0_b[tbase + t]);
            __hip_atomic_store(&exb[tbase + t],
                               tagw | __float_as_uint(v),
                               __ATOMIC_RELAXED, __HIP_MEMORY_SCOPE_AGENT);
        }
    }

    // ---- 6 mid layers: z = elu(elu(z @ W + b)); layer i reads exchange i
    for (int i = 0; i < 6; ++i) {
        const float* __restrict__ W = dnn_mid_W + (size_t)i * DNND * DNND;

        // preload this thread's 25 weight elems + bias; pin in VGPRs so the
        // loads are in flight during the poll (compiler would sink them).
        // Coalesced: per instruction a wave touches 4 rows x 16 consecutive
        // floats = 4x64B segments.
        float w[NK];
        #pragma unroll
        for (int j = 0; j < NK; ++j)
            w[j] = W[(kt + j * TT) * DNND + tbase + tt];
        float bmid = dnn_mid_b[i * DNND + tbase + tt];
        #pragma unroll
        for (int j = 0; j < NK; ++j) asm volatile("" : "+v"(w[j]));
        asm volatile("" : "+v"(bmid));

        // poll the tagged 8B slots of exchange i -> zs.
        // 400 slots over 256 threads: slot t for all, slot 256+t for t<144.
        const unsigned long long* s8 = exb + (size_t)i * EXU;
        {
            unsigned long long v;
            do {
                v = __hip_atomic_load(&s8[t], __ATOMIC_RELAXED,
                                      __HIP_MEMORY_SCOPE_AGENT);
            } while ((unsigned int)(v >> 32) != tag);
            zs[t] = __uint_as_float((unsigned int)v);
            if (t < DNND - BLK) {   // 144 tail slots
                do {
                    v = __hip_atomic_load(&s8[BLK + t], __ATOMIC_RELAXED,
                                          __HIP_MEMORY_SCOPE_AGENT);
                } while ((unsigned int)(v >> 32) != tag);
                zs[BLK + t] = __uint_as_float((unsigned int)v);
            }
        }
        __syncthreads();   // barrier 1: zs staged

        float acc = 0.f;
        #pragma unroll
        for (int j = 0; j < NK; ++j) acc += zs[kt + j * TT] * w[j];
        acc += __shfl_down(acc, 32, 64);
        acc += __shfl_down(acc, 16, 64);
        if (lane < TT) pr[wv * TT + lane] = acc;
        __syncthreads();   // barrier 2: partials visible

        if (t < TT) {
            float v = pr[t] + pr[TT + t] + pr[32 + t] + pr[48 + t] + bmid;
            v = elu1(elu1(v));
            if (i < 5) {
                __hip_atomic_store(&exb[(size_t)(i + 1) * EXU + tbase + t],
                                   tagw | __float_as_uint(v),
                                   __ATOMIC_RELAXED, __HIP_MEMORY_SCOPE_AGENT);
            } else {
                // fused final dot: 16 outputs x dnn_last_W, shuffle-reduced
                float p = v * wlast;   // wlast was loaded with tt==t here
                p += __shfl_down(p, 8, 16);
                p += __shfl_down(p, 4, 16);
                p += __shfl_down(p, 2, 16);
                p += __shfl_down(p, 1, 16);
                if (t == 0)
                    __hip_atomic_store(&finsl[blockIdx.x],
                                       tagw | __float_as_uint(p),
                                       __ATOMIC_RELAXED,
                                       __HIP_MEMORY_SCOPE_AGENT);
            }
        }
    }

    // ---- wg0, wave 0: gather 25 tagged partials by shuffle, sigmoid
    if (blockIdx.x == 0 && wv == 0) {
        float p = 0.f;
        if (lane < NWG) {
            unsigned long long v;
            do {
                v = __hip_atomic_load(&finsl[lane], __ATOMIC_RELAXED,
                                      __HIP_MEMORY_SCOPE_AGENT);
            } while ((unsigned int)(v >> 32) != tag);
            p = __uint_as_float((unsigned int)v);
        }
        p += __shfl_down(p, 32, 64);
        p += __shfl_down(p, 16, 64);
        p += __shfl_down(p, 8, 64);
        p += __shfl_down(p, 4, 64);
        p += __shfl_down(p, 2, 64);
        p += __shfl_down(p, 1, 64);
        if (lane == 0) {
            float s = p + dnn_last_b[0];
            out[0] = 1.f / (1.f + expf(-s));
            // advance the epoch: reaching here proves all 25 blocks
            // published (=> all read the old epoch), so this is race-free.
            __hip_atomic_store(epochp, tag, __ATOMIC_RELAXED,
                               __HIP_MEMORY_SCOPE_AGENT);
        }
    }
}

extern "C" void kernel_launch(void* const* d_in, const int* in_sizes, int n_in,
                              void* d_out, int out_size, void* d_ws, size_t ws_size,
                              hipStream_t stream) {
    // setup_inputs() order:
    //  0 x, 1 edge_attr, 2 gf1, 3 bn_in_g, 4 bn_in_b,
    //  5 gat0_W, 6 gat0_asrc, 7 gat0_adst, 8 gat0_bias,
    //  9 gat_mid_W, 10 gat_mid_asrc, 11 gat_mid_adst, 12 gat_mid_bias,
    // 13 bn_mid_g, 14 bn_mid_b,
    // 15 gat_last_W, 16 gat_last_asrc, 17 gat_last_adst, 18 gat_last_bias,
    // 19 bnpool_g, 20 bnpool_b, 21 ugp1_W, 22 ugp1_b, 23 ugp2_W, 24 ugp2_b,
    // 25 dnn0_W, 26 dnn0_b, 27 dnn_mid_W, 28 dnn_mid_b, 29 dnn_last_W,
    // 30 dnn_last_b, 31 edge_index, 32 batch
    const float* gf1        = (const float*)d_in[2];
    const float* bnpool_b   = (const float*)d_in[20];
    const float* ugp1_W     = (const float*)d_in[21];
    const float* ugp1_b     = (const float*)d_in[22];
    const float* ugp2_W     = (const float*)d_in[23];
    const float* ugp2_b     = (const float*)d_in[24];
    const float* dnn0_W     = (const float*)d_in[25];
    const float* dnn0_b     = (const float*)d_in[26];
    const float* dnn_mid_W  = (const float*)d_in[27];
    const float* dnn_mid_b  = (const float*)d_in[28];
    const float* dnn_last_W = (const float*)d_in[29];
    const float* dnn_last_b = (const float*)d_in[30];
    float* out = (float*)d_out;
    float* ws  = (float*)d_ws;

    // No memset: the epoch-tag protocol is self-initializing under any
    // workspace poison (see kernel comment). Single graph node.
    hipLaunchKernelGGL(GATGraphModel_tail_v8, dim3(NWG), dim3(BLK), 0, stream,
                       gf1, bnpool_b, ugp1_W, ugp1_b, ugp2_W, ugp2_b,
                       dnn0_W, dnn0_b, dnn_mid_W, dnn_mid_b,
                       dnn_last_W, dnn_last_b, out, ws);
}

// Round 8
// 17.357 us; speedup vs baseline: 2.1807x; 1.0775x over previous
//
#include <hip/hip_runtime.h>
#include <math.h>

// Problem constants (from reference)
#define POOLD 50
#define GFD   45
#define DNND  400
#define ZIN   (POOLD + GFD)   // 95

// Parallel decomposition: 25 wgs x 16 output columns = 400 outputs/layer.
// v9: BLK 256 -> 512 (8 waves). The per-layer critical path was the
// HBM-cold weight preload, MLP-bound at 4 waves (~6.4KB in flight /
// ~900cy latency ~ 1.4us/layer); 8 waves double the outstanding loads.
// Mapping: t = kt*16 + tt ; tt = output col (16 consecutive -> one 64B
// line per K-row, perfect coalescing), kt = 32-way K-split (NK=13, last
// iter guarded). Reduction: shfl_down(32)+shfl_down(16) intra-wave, then
// one 8-way LDS combine -> still 2 barriers/layer.
#define NWG 25
#define TT  16
#define KT  32
#define BLK 512               // 8 waves
#define NKF 12                // full k-iters; 13th only for kt<16

// Epoch-tagged exchange slots (v8 protocol, unchanged): 8B (tag|value)
// pairs; persistent epoch counter read once, publishes tagged epoch+1,
// block 0 advances the epoch after the final gather. Self-initializing
// under any workspace poison; no memset, single graph node.
#define EXU   512             // u64 slots per exchange buffer (4 KB)
#define NEX   6               // dnn0 out + mid0..mid4 out (mid5 is fused)

__device__ __forceinline__ float elu1(float x) {
    return x > 0.f ? x : expm1f(x);
}

// The entire GNN front-end is analytically dead:
//   global_mean_pool(BatchNorm_trainstats(h)) == bnpool_b  (exactly)
// so the output reduces to a tiny MLP on constants + gf1.
__global__ __launch_bounds__(BLK) void GATGraphModel_tail_v9(
    const float* __restrict__ gf1,        // [45]
    const float* __restrict__ bnpool_b,   // [14]
    const float* __restrict__ ugp1_W,     // [14,50]
    const float* __restrict__ ugp1_b,     // [50]
    const float* __restrict__ ugp2_W,     // [50,50]
    const float* __restrict__ ugp2_b,     // [50]
    const float* __restrict__ dnn0_W,     // [95,400]
    const float* __restrict__ dnn0_b,     // [400]
    const float* __restrict__ dnn_mid_W,  // [6,400,400]
    const float* __restrict__ dnn_mid_b,  // [6,400]
    const float* __restrict__ dnn_last_W, // [400,1]
    const float* __restrict__ dnn_last_b, // [1]
    float* __restrict__ out,              // [1]
    float* __restrict__ ws)               // 6*4KB exchanges + finsl + epoch
{
    __shared__ float zs[DNND];     // staged activation vector
    __shared__ float pr[128];      // 8 waves x 16 per-wave partials
    __shared__ float h2[POOLD];

    const int t     = threadIdx.x;
    const int tt    = t & (TT - 1);     // output col within wg's 16
    const int kt    = t >> 4;           // K-slice 0..31 (spans 8 waves)
    const int lane  = t & 63;
    const int wv    = t >> 6;           // wave 0..7
    const int tbase = blockIdx.x * TT;

    unsigned long long* exb    = (unsigned long long*)ws;  // 6 x 512 u64
    unsigned long long* finsl  = exb + (size_t)NEX * EXU;  // [25] tagged partials
    unsigned int*       epochp = (unsigned int*)(finsl + 32);

    // ---- epoch read (uniform; one RT, overlapped with the prologue)
    const unsigned int tag =
        __hip_atomic_load(epochp, __ATOMIC_RELAXED, __HIP_MEMORY_SCOPE_AGENT) + 1u;
    const unsigned long long tagw = (unsigned long long)tag << 32;

    // ---- preload dnn0 weight slice FIRST (overlaps the ugp dependent chain)
    float w0[3];
    #pragma unroll
    for (int j = 0; j < 3; ++j) {
        int k = kt + j * KT; if (k > ZIN - 1) k = ZIN - 1;  // clamp; predicated at use
        w0[j] = dnn0_W[k * DNND + tbase + tt];
    }
    #pragma unroll
    for (int j = 0; j < 3; ++j) asm volatile("" : "+v"(w0[j]));
    const float wlast = dnn_last_W[tbase + tt];   // fused-final weight

    // ---- ugp chain, redundantly in every wg (13 KB of cached reads —
    // cheaper than any exchange): p0 = bnpool_b ; h2 = p0@ugp1 + b
    if (t < POOLD) {
        float acc = ugp1_b[t];
        #pragma unroll
        for (int c = 0; c < 14; ++c) acc += bnpool_b[c] * ugp1_W[c * POOLD + t];
        h2[t] = acc;
    }
    __syncthreads();
    // p = h2 @ ugp2_W + b ; z = concat(p, gf1) -> zs[0:95]
    if (t < POOLD) {
        float acc = ugp2_b[t];
        #pragma unroll 10
        for (int k = 0; k < POOLD; ++k) acc += h2[k] * ugp2_W[k * POOLD + t];
        zs[t] = acc;
    } else if (t < ZIN) {
        zs[t] = gf1[t - POOLD];
    }
    __syncthreads();

    // ---- dnn0: elu(z95 @ dnn0_W + b) -> exchange 0
    {
        float acc = zs[kt] * w0[0];                 // kt < 32 < 95 always
        acc += zs[kt + KT] * w0[1];                 // kt+32 < 64 < 95 always
        if (kt + 2 * KT < ZIN) acc += zs[kt + 2 * KT] * w0[2];
        acc += __shfl_down(acc, 32, 64);    // fold kt&3 = 2,3 into 0,1
        acc += __shfl_down(acc, 16, 64);    // fold kt&3 = 1 into 0
        if (lane < TT) pr[wv * TT + lane] = acc;
        __syncthreads();
        if (t < TT) {
            float v = pr[t];
            #pragma unroll
            for (int w = 1; w < 8; ++w) v += pr[w * TT + t];
            v = elu1(v + dnn0_b[tbase + t]);
            __hip_atomic_store(&exb[tbase + t], tagw | __float_as_uint(v),
                               __ATOMIC_RELAXED, __HIP_MEMORY_SCOPE_AGENT);
        }
    }

    // ---- 6 mid layers: z = elu(elu(z @ W + b)); layer i reads exchange i
    for (int i = 0; i < 6; ++i) {
        const float* __restrict__ W = dnn_mid_W + (size_t)i * DNND * DNND;

        // preload this thread's 13 weight elems + bias; pin in VGPRs so the
        // loads are in flight during the poll (compiler would sink them).
        // Per instruction a wave touches 4 K-rows x 16 consecutive floats
        // = 4 full 64B lines; per-wg line ownership is exact (no overfetch).
        float w[13];
        #pragma unroll
        for (int j = 0; j < 13; ++j) {
            int k = kt + j * KT; if (k > DNND - 1) k = DNND - 1;  // clamp
            w[j] = W[k * DNND + tbase + tt];
        }
        float bmid = dnn_mid_b[i * DNND + tbase + tt];
        #pragma unroll
        for (int j = 0; j < 13; ++j) asm volatile("" : "+v"(w[j]));
        asm volatile("" : "+v"(bmid));

        // poll the tagged 8B slots of exchange i -> zs (one slot/thread)
        const unsigned long long* s8 = exb + (size_t)i * EXU;
        if (t < DNND) {
            unsigned long long v;
            do {
                v = __hip_atomic_load(&s8[t], __ATOMIC_RELAXED,
                                      __HIP_MEMORY_SCOPE_AGENT);
            } while ((unsigned int)(v >> 32) != tag);
            zs[t] = __uint_as_float((unsigned int)v);
        }
        __syncthreads();   // barrier 1: zs staged

        float acc = 0.f;
        #pragma unroll
        for (int j = 0; j < NKF; ++j) acc += zs[kt + j * KT] * w[j];
        if (kt < DNND - NKF * KT) acc += zs[kt + NKF * KT] * w[12];
        acc += __shfl_down(acc, 32, 64);
        acc += __shfl_down(acc, 16, 64);
        if (lane < TT) pr[wv * TT + lane] = acc;
        __syncthreads();   // barrier 2: partials visible

        if (t < TT) {
            float v = pr[t];
            #pragma unroll
            for (int w = 1; w < 8; ++w) v += pr[w * TT + t];
            v = elu1(elu1(v + bmid));
            if (i < 5) {
                __hip_atomic_store(&exb[(size_t)(i + 1) * EXU + tbase + t],
                                   tagw | __float_as_uint(v),
                                   __ATOMIC_RELAXED, __HIP_MEMORY_SCOPE_AGENT);
            } else {
                // fused final dot: 16 outputs x dnn_last_W, shuffle-reduced
                float p = v * wlast;   // for t<16, wlast = dnn_last_W[tbase+t]
                p += __shfl_down(p, 8, 16);
                p += __shfl_down(p, 4, 16);
                p += __shfl_down(p, 2, 16);
                p += __shfl_down(p, 1, 16);
                if (t == 0)
                    __hip_atomic_store(&finsl[blockIdx.x],
                                       tagw | __float_as_uint(p),
                                       __ATOMIC_RELAXED,
                                       __HIP_MEMORY_SCOPE_AGENT);
            }
        }
    }

    // ---- wg0, wave 0: gather 25 tagged partials by shuffle, sigmoid
    if (blockIdx.x == 0 && wv == 0) {
        float p = 0.f;
        if (lane < NWG) {
            unsigned long long v;
            do {
                v = __hip_atomic_load(&finsl[lane], __ATOMIC_RELAXED,
                                      __HIP_MEMORY_SCOPE_AGENT);
            } while ((unsigned int)(v >> 32) != tag);
            p = __uint_as_float((unsigned int)v);
        }
        p += __shfl_down(p, 32, 64);
        p += __shfl_down(p, 16, 64);
        p += __shfl_down(p, 8, 64);
        p += __shfl_down(p, 4, 64);
        p += __shfl_down(p, 2, 64);
        p += __shfl_down(p, 1, 64);
        if (lane == 0) {
            float s = p + dnn_last_b[0];
            out[0] = 1.f / (1.f + expf(-s));
            // advance the epoch: reaching here proves all 25 blocks
            // published (=> all read the old epoch), so this is race-free.
            __hip_atomic_store(epochp, tag, __ATOMIC_RELAXED,
                               __HIP_MEMORY_SCOPE_AGENT);
        }
    }
}

extern "C" void kernel_launch(void* const* d_in, const int* in_sizes, int n_in,
                              void* d_out, int out_size, void* d_ws, size_t ws_size,
                              hipStream_t stream) {
    // setup_inputs() order:
    //  0 x, 1 edge_attr, 2 gf1, 3 bn_in_g, 4 bn_in_b,
    //  5 gat0_W, 6 gat0_asrc, 7 gat0_adst, 8 gat0_bias,
    //  9 gat_mid_W, 10 gat_mid_asrc, 11 gat_mid_adst, 12 gat_mid_bias,
    // 13 bn_mid_g, 14 bn_mid_b,
    // 15 gat_last_W, 16 gat_last_asrc, 17 gat_last_adst, 18 gat_last_bias,
    // 19 bnpool_g, 20 bnpool_b, 21 ugp1_W, 22 ugp1_b, 23 ugp2_W, 24 ugp2_b,
    // 25 dnn0_W, 26 dnn0_b, 27 dnn_mid_W, 28 dnn_mid_b, 29 dnn_last_W,
    // 30 dnn_last_b, 31 edge_index, 32 batch
    const float* gf1        = (const float*)d_in[2];
    const float* bnpool_b   = (const float*)d_in[20];
    const float* ugp1_W     = (const float*)d_in[21];
    const float* ugp1_b     = (const float*)d_in[22];
    const float* ugp2_W     = (const float*)d_in[23];
    const float* ugp2_b     = (const float*)d_in[24];
    const float* dnn0_W     = (const float*)d_in[25];
    const float* dnn0_b     = (const float*)d_in[26];
    const float* dnn_mid_W  = (const float*)d_in[27];
    const float* dnn_mid_b  = (const float*)d_in[28];
    const float* dnn_last_W = (const float*)d_in[29];
    const float* dnn_last_b = (const float*)d_in[30];
    float* out = (float*)d_out;
    float* ws  = (float*)d_ws;

    // No memset: the epoch-tag protocol is self-initializing under any
    // workspace poison (see kernel comment). Single graph node.
    hipLaunchKernelGGL(GATGraphModel_tail_v9, dim3(NWG), dim3(BLK), 0, stream,
                       gf1, bnpool_b, ugp1_W, ugp1_b, ugp2_W, ugp2_b,
                       dnn0_W, dnn0_b, dnn_mid_W, dnn_mid_b,
                       dnn_last_W, dnn_last_b, out, ws);
}